// Round 4
// baseline (143.478 us; speedup 1.0000x reference)
//
#include <hip/hip_runtime.h>
#include <math.h>

// Problem constants (reference file)
#define B_ 2
#define H_ 1080
#define W_ 1920
#define K_ 2048
#define P_ 256

// Local window: sample centers within +/-23 of keypoint pixel (16*sqrt(2)
// rotation reach + rounding), +/-6 box radius -> +/-29; tile covers +/-30.
// Tile = 61x61 image pixels, local SAT = 62x62 (row 0 / col 0 zero).
// Stride 63 (odd) keeps column-direction LDS access conflict-free.
#define TW_ 61
#define SS_ 63                  // LDS row stride (floats)
#define SATN_ ((TW_ + 1) * SS_) // 3906 floats

__global__ __launch_bounds__(256) void bad_fused_kernel(
    const float* __restrict__ img, const float* __restrict__ kp,
    const float* __restrict__ orient,
    const float* __restrict__ oy1, const float* __restrict__ ox1,
    const float* __restrict__ oy2, const float* __restrict__ ox2,
    const float* __restrict__ thr, const int* __restrict__ radii,
    float* __restrict__ out) {
  __shared__ float S[SATN_];              // local SAT, S[a*SS_+b]
  __shared__ float wsum[4];

  int tid = threadIdx.x;
  int lane = tid & 63;
  int wv = tid >> 6;
  int bk = blockIdx.x;                    // b*K + k
  int b = bk >> 11;                       // K_ = 2048

  // Zero the ENTIRE SAT array: kernel output must not depend on LDS residue
  // from prior launches (round-3 failure mode: phase-2 graph replays saw our
  // own previous blocks' LDS and diverged).
  for (int i = tid; i < SATN_; i += 256) S[i] = 0.0f;

  // Per-thread control values (identical across threads; broadcast loads).
  // This is the round-2-proven control path — no tid-0/LDS broadcast.
  float kpy = kp[(size_t)bk * 2 + 0];
  float kpx = kp[(size_t)bk * 2 + 1];
  float validf = (kpy >= 0.0f) ? 1.0f : 0.0f;
  float y = fminf(fmaxf(kpy, 0.0f), (float)(H_ - 1));
  float x = fminf(fmaxf(kpx, 0.0f), (float)(W_ - 1));
  int iy = (int)rintf(y);
  int ix = (int)rintf(x);
  float theta = orient[((size_t)b * H_ + iy) * W_ + ix];
  double td = (double)theta;              // correctly-rounded fp32 sin/cos
  float st = (float)sin(td);
  float ct = (float)cos(td);
  int ty0 = iy - 30, tx0 = ix - 30;
  const float* imgb = img + (size_t)b * H_ * W_;
  __syncthreads();

  // ---- load 61x61 tile (zero outside image) into S[1..61][1..61] ----
  {
    int gx = tx0 + lane;
    bool cok = (lane < TW_) && (gx >= 0) && (gx < W_);
    for (int ly = wv; ly < TW_; ly += 4) {
      int gy = ty0 + ly;
      float v = 0.0f;
      if (cok && gy >= 0 && gy < H_) v = imgb[(size_t)gy * W_ + gx];
      if (lane < TW_) S[(ly + 1) * SS_ + lane + 1] = v;
    }
  }
  __syncthreads();

  // ---- row scan: horizontal inclusive prefix per row (wave shuffle) ----
  for (int ly = wv; ly < TW_; ly += 4) {
    float v = (lane < TW_) ? S[(ly + 1) * SS_ + lane + 1] : 0.0f;
    #pragma unroll
    for (int off = 1; off < 64; off <<= 1) {
      float n = __shfl_up(v, off, 64);
      if (lane >= off) v += n;
    }
    if (lane < TW_) S[(ly + 1) * SS_ + lane + 1] = v;
  }
  __syncthreads();

  // ---- col scan: vertical inclusive prefix per column (wave shuffle) ----
  for (int lx = wv; lx < TW_; lx += 4) {
    float v = (lane < TW_) ? S[(lane + 1) * SS_ + lx + 1] : 0.0f;
    #pragma unroll
    for (int off = 1; off < 64; off <<= 1) {
      float n = __shfl_up(v, off, 64);
      if (lane >= off) v += n;
    }
    if (lane < TW_) S[(lane + 1) * SS_ + lx + 1] = v;
  }
  __syncthreads();

  // ---- per-pair sampling ----
  int p = tid;
  float a_y1 = oy1[p], a_x1 = ox1[p], a_y2 = oy2[p], a_x2 = ox2[p];
  // strict fp32, no FMA contraction, same op order as reference
  float rdy1 = __fadd_rn(__fmul_rn(a_x1, st), __fmul_rn(a_y1, ct));
  float rdx1 = __fsub_rn(__fmul_rn(a_x1, ct), __fmul_rn(a_y1, st));
  float rdy2 = __fadd_rn(__fmul_rn(a_x2, st), __fmul_rn(a_y2, ct));
  float rdx2 = __fsub_rn(__fmul_rn(a_x2, ct), __fmul_rn(a_y2, st));
  float p1y = __fadd_rn(y, rdy1);
  float p1x = __fadd_rn(x, rdx1);
  float p2y = __fadd_rn(y, rdy2);
  float p2x = __fadd_rn(x, rdx2);

  int r = radii[p];
  float tt = 2.0f * (float)r + 1.0f;
  float w = __fdiv_rn(1.0f, __fmul_rn(tt, tt));   // fp32(1/(2r+1)^2)

  // sample 1 — all SAT indices clamped to [0, 61]: OOB impossible even if
  // the +/-23 reach analysis ever has a hole (clamps are no-ops otherwise).
  int jy = (int)fminf(fmaxf(rintf(p1y), 0.0f), (float)(H_ - 1));
  int jx = (int)fminf(fmaxf(rintf(p1x), 0.0f), (float)(W_ - 1));
  int a0 = min(max(jy - r - ty0, 0), TW_);
  int a1 = min(max(jy + r - ty0 + 1, 0), TW_);
  int c0 = min(max(jx - r - tx0, 0), TW_);
  int c1 = min(max(jx + r - tx0 + 1, 0), TW_);
  float s1 = ((S[a1 * SS_ + c1] - S[a0 * SS_ + c1])
              - S[a1 * SS_ + c0]) + S[a0 * SS_ + c0];
  float v1 = __fmul_rn(s1, w);
  // sample 2
  jy = (int)fminf(fmaxf(rintf(p2y), 0.0f), (float)(H_ - 1));
  jx = (int)fminf(fmaxf(rintf(p2x), 0.0f), (float)(W_ - 1));
  a0 = min(max(jy - r - ty0, 0), TW_);
  a1 = min(max(jy + r - ty0 + 1, 0), TW_);
  c0 = min(max(jx - r - tx0, 0), TW_);
  c1 = min(max(jx + r - tx0 + 1, 0), TW_);
  float s2 = ((S[a1 * SS_ + c1] - S[a0 * SS_ + c1])
              - S[a1 * SS_ + c0]) + S[a0 * SS_ + c0];
  float v2 = __fmul_rn(s2, w);

  float d = __fsub_rn(__fsub_rn(v1, v2), thr[p]);

  // block L2-norm over P=256: wave shuffle reduce + 4-wave LDS combine
  float sq = __fmul_rn(d, d);
  #pragma unroll
  for (int off = 32; off >= 1; off >>= 1) sq += __shfl_xor(sq, off, 64);
  if (lane == 0) wsum[wv] = sq;
  __syncthreads();
  float total = wsum[0] + wsum[1] + wsum[2] + wsum[3];
  float norm = sqrtf(total);
  float q = __fdiv_rn(d, fmaxf(norm, 1e-12f));
  out[(size_t)bk * P_ + p] = __fmul_rn(q, validf);
}

// ---------------------------------------------------------------------------

extern "C" void kernel_launch(void* const* d_in, const int* in_sizes, int n_in,
                              void* d_out, int out_size, void* d_ws, size_t ws_size,
                              hipStream_t stream) {
  const float* image    = (const float*)d_in[0];
  const float* kp       = (const float*)d_in[1];
  const float* orient   = (const float*)d_in[2];
  const float* oy1      = (const float*)d_in[3];
  const float* ox1      = (const float*)d_in[4];
  const float* oy2      = (const float*)d_in[5];
  const float* ox2      = (const float*)d_in[6];
  const float* thr      = (const float*)d_in[7];
  const int*   radii    = (const int*)d_in[8];
  float* out = (float*)d_out;

  bad_fused_kernel<<<B_ * K_, 256, 0, stream>>>(
      image, kp, orient, oy1, ox1, oy2, ox2, thr, radii, out);
}

// Round 5
// 116.615 us; speedup vs baseline: 1.2304x; 1.2304x over previous
//
#include <hip/hip_runtime.h>
#include <math.h>

// Problem constants (reference file)
#define B_ 2
#define H_ 1080
#define W_ 1920
#define K_ 2048
#define P_ 256

// Local window: sample centers within +/-23 of keypoint pixel (16*sqrt(2)
// rotation reach + rounding), +/-6 box radius -> +/-29; tile covers +/-30.
// Tile = 61x61 image pixels, local SAT = 62x62 (row 0 / col 0 zero).
// Stride 63 (odd): row-direction lane stride 63 -> bank (-lane+j)%32 and
// col-direction lane stride 1 -> both conflict-free for the serial scans.
#define TW_ 61
#define SS_ 63                  // LDS row stride (floats)
#define SATN_ ((TW_ + 1) * SS_) // 3906 floats

__global__ __launch_bounds__(256) void bad_fused_kernel(
    const float* __restrict__ img, const float* __restrict__ kp,
    const float* __restrict__ orient,
    const float* __restrict__ oy1, const float* __restrict__ ox1,
    const float* __restrict__ oy2, const float* __restrict__ ox2,
    const float* __restrict__ thr, const int* __restrict__ radii,
    float* __restrict__ out) {
  __shared__ float S[SATN_];              // local SAT, S[a*SS_+b]
  __shared__ float wsum[4];

  int tid = threadIdx.x;
  int lane = tid & 63;
  int wv = tid >> 6;
  int bk = blockIdx.x;                    // b*K + k
  int b = bk >> 11;                       // K_ = 2048

  // Per-thread control values (identical across threads; broadcast loads).
  float kpy = kp[(size_t)bk * 2 + 0];
  float kpx = kp[(size_t)bk * 2 + 1];
  float validf = (kpy >= 0.0f) ? 1.0f : 0.0f;
  float y = fminf(fmaxf(kpy, 0.0f), (float)(H_ - 1));
  float x = fminf(fmaxf(kpx, 0.0f), (float)(W_ - 1));
  int iy = (int)rintf(y);
  int ix = (int)rintf(x);
  float theta = orient[((size_t)b * H_ + iy) * W_ + ix];
  double td = (double)theta;              // correctly-rounded fp32 sin/cos
  float st = (float)sin(td);
  float ct = (float)cos(td);
  int ty0 = iy - 30, tx0 = ix - 30;
  const float* imgb = img + (size_t)b * H_ * W_;

  // Zero SAT row 0 (incl pads) and col 0. Every LDS cell that is ever read
  // is written every launch: row0/col0 here, interior [1..61][1..61] by the
  // tile load, sampling indices clamped to [0,61]. No residue dependence.
  if (tid < SS_) S[tid] = 0.0f;
  if (tid < TW_ + 1) S[tid * SS_] = 0.0f;

  // ---- load 61x61 tile (zero outside image) into S[1..61][1..61] ----
  {
    int gx = tx0 + lane;
    bool cok = (lane < TW_) && (gx >= 0) && (gx < W_);
    for (int ly = wv; ly < TW_; ly += 4) {
      int gy = ty0 + ly;
      float v = 0.0f;
      if (cok && gy >= 0 && gy < H_) v = imgb[(size_t)gy * W_ + gx];
      if (lane < TW_) S[(ly + 1) * SS_ + lane + 1] = v;
    }
  }
  __syncthreads();

  // ---- row scan: lane i of wave 0 owns row i; serial, double-accumulated
  // (each stored SAT entry correctly rounded -> no fp32 random walk) ----
  if (tid < TW_) {
    float* Rw = S + (tid + 1) * SS_;
    double acc = 0.0;
    #pragma unroll 4
    for (int j = 1; j <= TW_; ++j) {
      acc += (double)Rw[j];
      Rw[j] = (float)acc;
    }
  }
  __syncthreads();

  // ---- col scan: lane i of wave 0 owns column i; serial, double-acc ----
  if (tid < TW_) {
    float* Cw = S + (tid + 1);
    double acc = 0.0;
    #pragma unroll 4
    for (int j = 1; j <= TW_; ++j) {
      acc += (double)Cw[(size_t)j * SS_];
      Cw[(size_t)j * SS_] = (float)acc;
    }
  }
  __syncthreads();

  // ---- per-pair sampling ----
  int p = tid;
  float a_y1 = oy1[p], a_x1 = ox1[p], a_y2 = oy2[p], a_x2 = ox2[p];
  // strict fp32, no FMA contraction, same op order as reference
  float rdy1 = __fadd_rn(__fmul_rn(a_x1, st), __fmul_rn(a_y1, ct));
  float rdx1 = __fsub_rn(__fmul_rn(a_x1, ct), __fmul_rn(a_y1, st));
  float rdy2 = __fadd_rn(__fmul_rn(a_x2, st), __fmul_rn(a_y2, ct));
  float rdx2 = __fsub_rn(__fmul_rn(a_x2, ct), __fmul_rn(a_y2, st));
  float p1y = __fadd_rn(y, rdy1);
  float p1x = __fadd_rn(x, rdx1);
  float p2y = __fadd_rn(y, rdy2);
  float p2x = __fadd_rn(x, rdx2);

  int r = radii[p];
  float tt = 2.0f * (float)r + 1.0f;
  float w = __fdiv_rn(1.0f, __fmul_rn(tt, tt));   // fp32(1/(2r+1)^2)

  // sample 1 — SAT indices clamped to [0, 61]: provably no-ops (reach
  // |jy-iy| <= 23, r <= 6 -> indices in [1,60]), kept as OOB hard stop.
  int jy = (int)fminf(fmaxf(rintf(p1y), 0.0f), (float)(H_ - 1));
  int jx = (int)fminf(fmaxf(rintf(p1x), 0.0f), (float)(W_ - 1));
  int a0 = min(max(jy - r - ty0, 0), TW_);
  int a1 = min(max(jy + r - ty0 + 1, 0), TW_);
  int c0 = min(max(jx - r - tx0, 0), TW_);
  int c1 = min(max(jx + r - tx0 + 1, 0), TW_);
  float s1 = ((S[a1 * SS_ + c1] - S[a0 * SS_ + c1])
              - S[a1 * SS_ + c0]) + S[a0 * SS_ + c0];
  float v1 = __fmul_rn(s1, w);
  // sample 2
  jy = (int)fminf(fmaxf(rintf(p2y), 0.0f), (float)(H_ - 1));
  jx = (int)fminf(fmaxf(rintf(p2x), 0.0f), (float)(W_ - 1));
  a0 = min(max(jy - r - ty0, 0), TW_);
  a1 = min(max(jy + r - ty0 + 1, 0), TW_);
  c0 = min(max(jx - r - tx0, 0), TW_);
  c1 = min(max(jx + r - tx0 + 1, 0), TW_);
  float s2 = ((S[a1 * SS_ + c1] - S[a0 * SS_ + c1])
              - S[a1 * SS_ + c0]) + S[a0 * SS_ + c0];
  float v2 = __fmul_rn(s2, w);

  float d = __fsub_rn(__fsub_rn(v1, v2), thr[p]);

  // block L2-norm over P=256: wave shuffle reduce + 4-wave LDS combine
  float sq = __fmul_rn(d, d);
  #pragma unroll
  for (int off = 32; off >= 1; off >>= 1) sq += __shfl_xor(sq, off, 64);
  if (lane == 0) wsum[wv] = sq;
  __syncthreads();
  float total = wsum[0] + wsum[1] + wsum[2] + wsum[3];
  float norm = sqrtf(total);
  float q = __fdiv_rn(d, fmaxf(norm, 1e-12f));
  out[(size_t)bk * P_ + p] = __fmul_rn(q, validf);
}

// ---------------------------------------------------------------------------

extern "C" void kernel_launch(void* const* d_in, const int* in_sizes, int n_in,
                              void* d_out, int out_size, void* d_ws, size_t ws_size,
                              hipStream_t stream) {
  const float* image    = (const float*)d_in[0];
  const float* kp       = (const float*)d_in[1];
  const float* orient   = (const float*)d_in[2];
  const float* oy1      = (const float*)d_in[3];
  const float* ox1      = (const float*)d_in[4];
  const float* oy2      = (const float*)d_in[5];
  const float* ox2      = (const float*)d_in[6];
  const float* thr      = (const float*)d_in[7];
  const int*   radii    = (const int*)d_in[8];
  float* out = (float*)d_out;

  bad_fused_kernel<<<B_ * K_, 256, 0, stream>>>(
      image, kp, orient, oy1, ox1, oy2, ox2, thr, radii, out);
}

// Round 6
// 108.145 us; speedup vs baseline: 1.3267x; 1.0783x over previous
//
#include <hip/hip_runtime.h>
#include <math.h>

// Problem constants (reference file)
#define B_ 2
#define H_ 1080
#define W_ 1920
#define K_ 2048
#define P_ 256

// Local window: sample centers within +/-23 of keypoint pixel (16*sqrt(2)
// rotation reach + rounding), +/-6 box radius -> +/-29; tile covers +/-30.
// Tile = 61x61 image pixels, local SAT rows 0..64 x cols 0..66:
//   row 0 / col 0 zero borders, data rows/cols 1..61,
//   pad cols 62..64 and pad rows 62..64 zero so the segmented scans can use
//   uniform 16-element segments (4 segments cover indices 1..64).
// SS_=67 (odd): scan-phase lane->bank aliasing is exactly 2-way (free).
#define TW_ 61
#define SS_ 67                   // LDS row stride (floats)
#define NROWS_ 65                // SAT rows 0..64
#define SATN_ (NROWS_ * SS_ + 1) // 4356 floats

__global__ __launch_bounds__(256) void bad_fused_kernel(
    const float* __restrict__ img, const float* __restrict__ kp,
    const float* __restrict__ orient,
    const float* __restrict__ oy1, const float* __restrict__ ox1,
    const float* __restrict__ oy2, const float* __restrict__ ox2,
    const float* __restrict__ thr, const int* __restrict__ radii,
    float* __restrict__ out) {
  __shared__ float S[SATN_];              // local SAT, S[a*SS_+c]
  __shared__ float wsum[4];

  int tid = threadIdx.x;
  int lane = tid & 63;
  int wv = tid >> 6;
  int bk = blockIdx.x;                    // b*K + k
  int b = bk >> 11;                       // K_ = 2048

  // Per-thread control values (identical across threads; broadcast loads).
  // FROZEN coordinate path (absmax-critical): strict fp32 + double sin/cos.
  float kpy = kp[(size_t)bk * 2 + 0];
  float kpx = kp[(size_t)bk * 2 + 1];
  float validf = (kpy >= 0.0f) ? 1.0f : 0.0f;
  float y = fminf(fmaxf(kpy, 0.0f), (float)(H_ - 1));
  float x = fminf(fmaxf(kpx, 0.0f), (float)(W_ - 1));
  int iy = (int)rintf(y);
  int ix = (int)rintf(x);
  float theta = orient[((size_t)b * H_ + iy) * W_ + ix];
  double td = (double)theta;              // correctly-rounded fp32 sin/cos
  float st = (float)sin(td);
  float ct = (float)cos(td);
  int ty0 = iy - 30, tx0 = ix - 30;
  const float* imgb = img + (size_t)b * H_ * W_;

  // ---- zero borders/pads (disjoint from tile cells -> no barrier needed
  // before the tile writes). Every LDS cell ever read is written every
  // launch: no dependence on residue from prior launches/blocks.
  if (tid < SS_) S[tid] = 0.0f;                          // row 0
  if (tid < 3 * SS_) S[62 * SS_ + tid] = 0.0f;           // pad rows 62..64
  if (tid < TW_) S[(tid + 1) * SS_] = 0.0f;              // col 0, rows 1..61
  if (tid == 0) S[SATN_ - 1] = 0.0f;                     // tail pad

  // ---- tile load: wave wv owns rows ly = wv+4k; register-staged in chunks
  // of 8 so 8 global loads are in flight (round-5 was 1-in-flight at
  // VGPR=20 -> per-load latency serialization). Lanes 61..63 write zeros
  // into pad cols 62..64.
  {
    int gx = tx0 + lane;
    bool cok = (lane < TW_) && (gx >= 0) && (gx < W_);
    #pragma unroll
    for (int c = 0; c < 2; ++c) {
      float v[8];
      #pragma unroll
      for (int k = 0; k < 8; ++k) {
        int ly = wv + 4 * (8 * c + k);
        int gy = ty0 + ly;
        v[k] = 0.0f;
        if (ly < TW_ && cok && gy >= 0 && gy < H_)
          v[k] = imgb[(size_t)gy * W_ + gx];
      }
      #pragma unroll
      for (int k = 0; k < 8; ++k) {
        int ly = wv + 4 * (8 * c + k);
        if (ly < TW_) S[(ly + 1) * SS_ + lane + 1] = v[k];
      }
    }
  }
  __syncthreads();

  // ---- row scan, segmented: thread 4i+s owns cols [16s+1 .. 16s+16] of row
  // i+1 (pads zero). passA: register sum; wave-local 4-way shuffle scan for
  // the segment offset (threads of a row are adjacent -> same wave, no
  // barrier); passB: write double-accumulated prefix as fp32.
  if (tid < 244) {
    int i = tid >> 2, s = tid & 3;
    float* Rw = S + (i + 1) * SS_ + 16 * s + 1;
    float v[16];
    #pragma unroll
    for (int k = 0; k < 16; ++k) v[k] = Rw[k];
    double acc = 0.0;
    #pragma unroll
    for (int k = 0; k < 16; ++k) acc += (double)v[k];
    double inc = acc;
    double n1 = __shfl_up(inc, 1, 64); if (s >= 1) inc += n1;
    double n2 = __shfl_up(inc, 2, 64); if (s >= 2) inc += n2;
    double e = __shfl_up(inc, 1, 64);
    double a2 = (s >= 1) ? e : 0.0;
    #pragma unroll
    for (int k = 0; k < 16; ++k) { a2 += (double)v[k]; Rw[k] = (float)a2; }
  }
  __syncthreads();

  // ---- col scan, segmented: thread 4i+s owns rows [16s+1 .. 16s+16] of col
  // i+1 (pad rows 62..64 are zero: row scan never touches them).
  if (tid < 244) {
    int i = tid >> 2, s = tid & 3;
    float* Cw = S + (16 * s + 1) * SS_ + (i + 1);
    float v[16];
    #pragma unroll
    for (int k = 0; k < 16; ++k) v[k] = Cw[k * SS_];
    double acc = 0.0;
    #pragma unroll
    for (int k = 0; k < 16; ++k) acc += (double)v[k];
    double inc = acc;
    double n1 = __shfl_up(inc, 1, 64); if (s >= 1) inc += n1;
    double n2 = __shfl_up(inc, 2, 64); if (s >= 2) inc += n2;
    double e = __shfl_up(inc, 1, 64);
    double a2 = (s >= 1) ? e : 0.0;
    #pragma unroll
    for (int k = 0; k < 16; ++k) { a2 += (double)v[k]; Cw[k * SS_] = (float)a2; }
  }
  __syncthreads();

  // ---- per-pair sampling (FROZEN coordinate path) ----
  int p = tid;
  float a_y1 = oy1[p], a_x1 = ox1[p], a_y2 = oy2[p], a_x2 = ox2[p];
  float rdy1 = __fadd_rn(__fmul_rn(a_x1, st), __fmul_rn(a_y1, ct));
  float rdx1 = __fsub_rn(__fmul_rn(a_x1, ct), __fmul_rn(a_y1, st));
  float rdy2 = __fadd_rn(__fmul_rn(a_x2, st), __fmul_rn(a_y2, ct));
  float rdx2 = __fsub_rn(__fmul_rn(a_x2, ct), __fmul_rn(a_y2, st));
  float p1y = __fadd_rn(y, rdy1);
  float p1x = __fadd_rn(x, rdx1);
  float p2y = __fadd_rn(y, rdy2);
  float p2x = __fadd_rn(x, rdx2);

  int r = radii[p];
  float tt = 2.0f * (float)r + 1.0f;
  float w = __fdiv_rn(1.0f, __fmul_rn(tt, tt));   // fp32(1/(2r+1)^2)

  // sample 1 — SAT indices clamped to [0, 61]: provably no-ops (reach
  // |jy-iy| <= 23, r <= 6 -> indices in [1,60]), kept as OOB hard stop.
  int jy = (int)fminf(fmaxf(rintf(p1y), 0.0f), (float)(H_ - 1));
  int jx = (int)fminf(fmaxf(rintf(p1x), 0.0f), (float)(W_ - 1));
  int a0 = min(max(jy - r - ty0, 0), TW_);
  int a1 = min(max(jy + r - ty0 + 1, 0), TW_);
  int c0 = min(max(jx - r - tx0, 0), TW_);
  int c1 = min(max(jx + r - tx0 + 1, 0), TW_);
  float s1 = ((S[a1 * SS_ + c1] - S[a0 * SS_ + c1])
              - S[a1 * SS_ + c0]) + S[a0 * SS_ + c0];
  float v1 = __fmul_rn(s1, w);
  // sample 2
  jy = (int)fminf(fmaxf(rintf(p2y), 0.0f), (float)(H_ - 1));
  jx = (int)fminf(fmaxf(rintf(p2x), 0.0f), (float)(W_ - 1));
  a0 = min(max(jy - r - ty0, 0), TW_);
  a1 = min(max(jy + r - ty0 + 1, 0), TW_);
  c0 = min(max(jx - r - tx0, 0), TW_);
  c1 = min(max(jx + r - tx0 + 1, 0), TW_);
  float s2 = ((S[a1 * SS_ + c1] - S[a0 * SS_ + c1])
              - S[a1 * SS_ + c0]) + S[a0 * SS_ + c0];
  float v2 = __fmul_rn(s2, w);

  float d = __fsub_rn(__fsub_rn(v1, v2), thr[p]);

  // block L2-norm over P=256: wave shuffle reduce + 4-wave LDS combine
  float sq = __fmul_rn(d, d);
  #pragma unroll
  for (int off = 32; off >= 1; off >>= 1) sq += __shfl_xor(sq, off, 64);
  if (lane == 0) wsum[wv] = sq;
  __syncthreads();
  float total = wsum[0] + wsum[1] + wsum[2] + wsum[3];
  float norm = sqrtf(total);
  float q = __fdiv_rn(d, fmaxf(norm, 1e-12f));
  out[(size_t)bk * P_ + p] = __fmul_rn(q, validf);
}

// ---------------------------------------------------------------------------

extern "C" void kernel_launch(void* const* d_in, const int* in_sizes, int n_in,
                              void* d_out, int out_size, void* d_ws, size_t ws_size,
                              hipStream_t stream) {
  const float* image    = (const float*)d_in[0];
  const float* kp       = (const float*)d_in[1];
  const float* orient   = (const float*)d_in[2];
  const float* oy1      = (const float*)d_in[3];
  const float* ox1      = (const float*)d_in[4];
  const float* oy2      = (const float*)d_in[5];
  const float* ox2      = (const float*)d_in[6];
  const float* thr      = (const float*)d_in[7];
  const int*   radii    = (const int*)d_in[8];
  float* out = (float*)d_out;

  bad_fused_kernel<<<B_ * K_, 256, 0, stream>>>(
      image, kp, orient, oy1, ox1, oy2, ox2, thr, radii, out);
}

// Round 7
// 105.022 us; speedup vs baseline: 1.3662x; 1.0297x over previous
//
#include <hip/hip_runtime.h>
#include <math.h>

// Problem constants (reference file)
#define B_ 2
#define H_ 1080
#define W_ 1920
#define K_ 2048
#define P_ 256

// Borderless local SAT. tx0 = (ix-30) & ~3 (4-aligned -> 16B-aligned global
// float4 loads), ty0 = iy-30. Tile rows 0..60 (gy=ty0+ri), cols 0..63
// (gx=tx0+ci). After scans S[a][c] = sum of tile rows 0..a, cols 0..c.
// Sampling uses exclusive indices a0=jy-r-ty0-1 >= 0, c0=jx-r-tx0-1 >= 0
// (proof: jy >= iy-23, r <= 6, ty0 = iy-30 -> a0 >= 0; same for cols with
// tx0 >= ix-33 -> c0 >= 0; a1 <= 59, c1 <= 62). Pad rows 61..63 zero so the
// col scan uses uniform 16-row segments. SS_=68 (mult of 4): row-scan b128
// stores and col-scan b64 ops are streaming-optimal on 32 banks.
#define SS_ 68                   // LDS row stride (floats)
#define SATN_ (64 * SS_)         // 4352 floats = 17408 B

// ---------------------------------------------------------------------------
// Per-keypoint precompute: FROZEN coordinate path (strict fp32 clamps/rint,
// double sin/cos rounded to fp32 — bit-identical to prior rounds). Hoisted
// here so 64 waves do it once instead of 16384 waves in the main kernel.
// Writes every slot every launch (d_ws is re-poisoned before each replay).
// ---------------------------------------------------------------------------
__global__ __launch_bounds__(256) void kp_pre_kernel(
    const float* __restrict__ kp, const float* __restrict__ orient,
    float* __restrict__ ctl) {
  int bk = blockIdx.x * blockDim.x + threadIdx.x;
  if (bk >= B_ * K_) return;
  int b = bk >> 11;                       // K_ = 2048
  float kpy = kp[(size_t)bk * 2 + 0];
  float kpx = kp[(size_t)bk * 2 + 1];
  float validf = (kpy >= 0.0f) ? 1.0f : 0.0f;
  float y = fminf(fmaxf(kpy, 0.0f), (float)(H_ - 1));
  float x = fminf(fmaxf(kpx, 0.0f), (float)(W_ - 1));
  int iy = (int)rintf(y);
  int ix = (int)rintf(x);
  float theta = orient[((size_t)b * H_ + iy) * W_ + ix];
  double td = (double)theta;
  float st = (float)sin(td);
  float ct = (float)cos(td);
  int ty0 = iy - 30;
  int tx0 = (ix - 30) & ~3;               // 4-aligned (works for negatives)
  float4 c0v, c1v;
  c0v.x = y; c0v.y = x; c0v.z = st; c0v.w = ct;
  c1v.x = validf; c1v.y = __int_as_float(ty0);
  c1v.z = __int_as_float(tx0); c1v.w = 0.0f;
  float4* c4 = (float4*)(ctl + (size_t)bk * 8);
  c4[0] = c0v;
  c4[1] = c1v;
}

// ---------------------------------------------------------------------------
// Fused: register row-scan of the tile + LDS col-scan + sampling + norm.
// ---------------------------------------------------------------------------
__global__ __launch_bounds__(256) void bad_fused_kernel(
    const float* __restrict__ img, const float* __restrict__ ctl,
    const float* __restrict__ oy1, const float* __restrict__ ox1,
    const float* __restrict__ oy2, const float* __restrict__ ox2,
    const float* __restrict__ thr, const int* __restrict__ radii,
    float* __restrict__ out) {
  __shared__ float S[SATN_];
  __shared__ float wsum[4];

  int tid = threadIdx.x;
  int lane = tid & 63;
  int wv = tid >> 6;
  int bk = blockIdx.x;
  int b = bk >> 11;

  const float4* c4 = (const float4*)(ctl + (size_t)bk * 8);
  float4 ca = c4[0];
  float4 cb = c4[1];
  float y = ca.x, x = ca.y, st = ca.z, ct = ca.w;
  float validf = cb.x;
  int ty0 = __float_as_int(cb.y);
  int tx0 = __float_as_int(cb.z);
  const float* imgb = img + (size_t)b * H_ * W_;

  // zero pad rows 61..63 (never touched by row scan; read by col scan).
  if (tid < 3 * SS_) S[61 * SS_ + tid] = 0.0f;

  // ---- fused tile-load + row scan: thread 4i+s owns row i, cols 16s..16s+15
  if (tid < 244) {
    int i = tid >> 2, s = tid & 3;
    int gy = ty0 + i;
    int gx0 = tx0 + 16 * s;
    bool gyok = (gy >= 0) && (gy < H_);
    bool colfast = (tx0 >= 0) && (tx0 + 64 <= W_);   // block-uniform
    float v[16];
    if (gyok && colfast) {
      const float4* rp = (const float4*)(imgb + (size_t)gy * W_ + gx0);
      #pragma unroll
      for (int m = 0; m < 4; ++m) {
        float4 t = rp[m];
        v[4 * m + 0] = t.x; v[4 * m + 1] = t.y;
        v[4 * m + 2] = t.z; v[4 * m + 3] = t.w;
      }
    } else if (gyok) {
      #pragma unroll
      for (int k = 0; k < 16; ++k) {
        int gx = gx0 + k;
        v[k] = (gx >= 0 && gx < W_) ? imgb[(size_t)gy * W_ + gx] : 0.0f;
      }
    } else {
      #pragma unroll
      for (int k = 0; k < 16; ++k) v[k] = 0.0f;
    }
    #pragma unroll
    for (int k = 1; k < 16; ++k) v[k] += v[k - 1];   // in-register prefix
    // cross-segment offset: 4 segments are adjacent lanes (tid = 4i+s)
    float inc = v[15];
    float n1 = __shfl_up(inc, 1, 64); if (s >= 1) inc += n1;
    float n2 = __shfl_up(inc, 2, 64); if (s >= 2) inc += n2;
    float e = __shfl_up(inc, 1, 64);
    float off = (s >= 1) ? e : 0.0f;
    float* Rw = S + i * SS_ + 16 * s;                // 16B-aligned
    #pragma unroll
    for (int m = 0; m < 4; ++m) {
      float4 t;
      t.x = v[4 * m + 0] + off; t.y = v[4 * m + 1] + off;
      t.z = v[4 * m + 2] + off; t.w = v[4 * m + 3] + off;
      ((float4*)Rw)[m] = t;
    }
  }
  __syncthreads();

  // ---- col scan: thread 4j+s owns cols 2j..2j+1, rows 16s..16s+15 (b64)
  if (tid < 128) {
    int j = tid >> 2, s = tid & 3;
    float* Cb = S + (16 * s) * SS_ + 2 * j;
    float2 rv[16];
    #pragma unroll
    for (int k = 0; k < 16; ++k) rv[k] = *(float2*)(Cb + k * SS_);
    #pragma unroll
    for (int k = 1; k < 16; ++k) { rv[k].x += rv[k-1].x; rv[k].y += rv[k-1].y; }
    float ix_ = rv[15].x, iy_ = rv[15].y;
    float nx1 = __shfl_up(ix_, 1, 64), ny1 = __shfl_up(iy_, 1, 64);
    if (s >= 1) { ix_ += nx1; iy_ += ny1; }
    float nx2 = __shfl_up(ix_, 2, 64), ny2 = __shfl_up(iy_, 2, 64);
    if (s >= 2) { ix_ += nx2; iy_ += ny2; }
    float ex = __shfl_up(ix_, 1, 64), ey = __shfl_up(iy_, 1, 64);
    float ofx = (s >= 1) ? ex : 0.0f, ofy = (s >= 1) ? ey : 0.0f;
    #pragma unroll
    for (int k = 0; k < 16; ++k) {
      float2 t; t.x = rv[k].x + ofx; t.y = rv[k].y + ofy;
      *(float2*)(Cb + k * SS_) = t;
    }
  }
  __syncthreads();

  // ---- per-pair sampling (FROZEN coordinate path) ----
  int p = tid;
  float a_y1 = oy1[p], a_x1 = ox1[p], a_y2 = oy2[p], a_x2 = ox2[p];
  float rdy1 = __fadd_rn(__fmul_rn(a_x1, st), __fmul_rn(a_y1, ct));
  float rdx1 = __fsub_rn(__fmul_rn(a_x1, ct), __fmul_rn(a_y1, st));
  float rdy2 = __fadd_rn(__fmul_rn(a_x2, st), __fmul_rn(a_y2, ct));
  float rdx2 = __fsub_rn(__fmul_rn(a_x2, ct), __fmul_rn(a_y2, st));
  float p1y = __fadd_rn(y, rdy1);
  float p1x = __fadd_rn(x, rdx1);
  float p2y = __fadd_rn(y, rdy2);
  float p2x = __fadd_rn(x, rdx2);

  int r = radii[p];
  float tt = 2.0f * (float)r + 1.0f;
  float w = __fdiv_rn(1.0f, __fmul_rn(tt, tt));   // fp32(1/(2r+1)^2)

  // sample 1 — indices provably in [0,63]; clamps kept as OOB hard stop.
  int jy = (int)fminf(fmaxf(rintf(p1y), 0.0f), (float)(H_ - 1));
  int jx = (int)fminf(fmaxf(rintf(p1x), 0.0f), (float)(W_ - 1));
  int a0 = min(max(jy - r - ty0 - 1, 0), 63);
  int a1 = min(max(jy + r - ty0, 0), 63);
  int c0 = min(max(jx - r - tx0 - 1, 0), 63);
  int c1 = min(max(jx + r - tx0, 0), 63);
  float s1 = ((S[a1 * SS_ + c1] - S[a0 * SS_ + c1])
              - S[a1 * SS_ + c0]) + S[a0 * SS_ + c0];
  float v1 = __fmul_rn(s1, w);
  // sample 2
  jy = (int)fminf(fmaxf(rintf(p2y), 0.0f), (float)(H_ - 1));
  jx = (int)fminf(fmaxf(rintf(p2x), 0.0f), (float)(W_ - 1));
  a0 = min(max(jy - r - ty0 - 1, 0), 63);
  a1 = min(max(jy + r - ty0, 0), 63);
  c0 = min(max(jx - r - tx0 - 1, 0), 63);
  c1 = min(max(jx + r - tx0, 0), 63);
  float s2 = ((S[a1 * SS_ + c1] - S[a0 * SS_ + c1])
              - S[a1 * SS_ + c0]) + S[a0 * SS_ + c0];
  float v2 = __fmul_rn(s2, w);

  float d = __fsub_rn(__fsub_rn(v1, v2), thr[p]);

  // block L2-norm over P=256
  float sq = __fmul_rn(d, d);
  #pragma unroll
  for (int off = 32; off >= 1; off >>= 1) sq += __shfl_xor(sq, off, 64);
  if (lane == 0) wsum[wv] = sq;
  __syncthreads();
  float total = wsum[0] + wsum[1] + wsum[2] + wsum[3];
  float norm = sqrtf(total);
  float q = __fdiv_rn(d, fmaxf(norm, 1e-12f));
  out[(size_t)bk * P_ + p] = __fmul_rn(q, validf);
}

// ---------------------------------------------------------------------------

extern "C" void kernel_launch(void* const* d_in, const int* in_sizes, int n_in,
                              void* d_out, int out_size, void* d_ws, size_t ws_size,
                              hipStream_t stream) {
  const float* image    = (const float*)d_in[0];
  const float* kp       = (const float*)d_in[1];
  const float* orient   = (const float*)d_in[2];
  const float* oy1      = (const float*)d_in[3];
  const float* ox1      = (const float*)d_in[4];
  const float* oy2      = (const float*)d_in[5];
  const float* ox2      = (const float*)d_in[6];
  const float* thr      = (const float*)d_in[7];
  const int*   radii    = (const int*)d_in[8];
  float* out = (float*)d_out;
  float* ctl = (float*)d_ws;              // 4096 * 8 floats = 128 KB

  kp_pre_kernel<<<(B_ * K_ + 255) / 256, 256, 0, stream>>>(kp, orient, ctl);
  bad_fused_kernel<<<B_ * K_, 256, 0, stream>>>(
      image, ctl, oy1, ox1, oy2, ox2, thr, radii, out);
}